// Round 6
// baseline (1898.885 us; speedup 1.0000x reference)
//
#include <hip/hip_runtime.h>

// Problem constants: V=27, E=64, H=128, B=256, S=512 (enc and dec)
#define V_ 27
#define E_ 64
#define H_ 128
#define S_ 512
#define SCL 2.8853900817779268f   // 2*log2(e): tanh(z) = 1 - 2/(exp2(SCL*z)+1)

typedef float f32x2 __attribute__((ext_vector_type(2)));
typedef float f32x4 __attribute__((ext_vector_type(4)));

// ---- packed fp32 FMA (v_pk_fma_f32 on gfx950; fp32-exact, no precision risk) ----
#if __has_builtin(__builtin_elementwise_fma)
#define EFMA(H2, W2, A) (A) = __builtin_elementwise_fma((f32x2)(H2), (f32x2)(W2), (A))
#else
#define EFMA(H2, W2, A) do { f32x2 _h = (H2), _w = (W2); \
    (A).x = fmaf(_h.x, _w.x, (A).x); (A).y = fmaf(_h.y, _w.y, (A).y); } while (0)
#endif
#define LO2(Q) __builtin_shufflevector((Q), (Q), 0, 1)
#define HI2(Q) __builtin_shufflevector((Q), (Q), 2, 3)

// Hazard-safe DPP add (compiler inserts required wait states).
template<int CTRL>
__device__ __forceinline__ float dpp_add(float x) {
    int y = __builtin_amdgcn_update_dpp(0, __builtin_bit_cast(int, x), CTRL, 0xF, 0xF, true);
    return x + __builtin_bit_cast(float, y);
}
#define QP_1032 0xB1   // quad_perm [1,0,3,2]  (xor 1)
#define QP_2301 0x4E   // quad_perm [2,3,0,1]  (xor 2)

// tanh from pre-scaled argument P = SCL*z:  tanh(z) = 1 - 2/(exp2(P)+1)
__device__ __forceinline__ float tanh_ps(float P) {
#if __has_builtin(__builtin_amdgcn_exp2f)
    float e = __builtin_amdgcn_exp2f(P);
#else
    float e = __expf(P * 0.69314718055994531f);
#endif
#if __has_builtin(__builtin_amdgcn_rcpf)
    float q = __builtin_amdgcn_rcpf(e + 1.0f);
    return fmaf(-2.0f, q, 1.0f);
#else
    return 1.0f - __fdividef(2.0f, e + 1.0f);
#endif
}

// ---------- prep kernel: T[tbl][v][j] = SCL*(b[j] + sum_e embed[v][e]*Wx[e][j]) ----------
__global__ void prep_T(const float* __restrict__ embed,
                       const float* __restrict__ eWx, const float* __restrict__ eb,
                       const float* __restrict__ dWx, const float* __restrict__ db_,
                       float* __restrict__ Tg) {
    int tbl = blockIdx.x / V_;
    int v   = blockIdx.x - tbl * V_;
    int j   = threadIdx.x;
    const float* Wx = tbl ? dWx : eWx;
    const float* bb = tbl ? db_ : eb;
    float s = bb[j];
    #pragma unroll
    for (int e = 0; e < E_; ++e) s = fmaf(embed[v * E_ + e], Wx[e * H_ + j], s);
    Tg[tbl * V_ * H_ + v * H_ + j] = s * SCL;
}

// ---- register pins: force weight residency across the loop (defeat remat/sinking) ----
#define PINW() do { \
    asm volatile("" : "+v"(WQ[0]),  "+v"(WQ[1]),  "+v"(WQ[2]),  "+v"(WQ[3]),  \
                      "+v"(WQ[4]),  "+v"(WQ[5]),  "+v"(WQ[6]),  "+v"(WQ[7]),  \
                      "+v"(WQ[8]),  "+v"(WQ[9]),  "+v"(WQ[10]), "+v"(WQ[11]), \
                      "+v"(WQ[12]), "+v"(WQ[13]), "+v"(WQ[14]), "+v"(WQ[15])); \
    asm volatile("" : "+v"(WQ[16]), "+v"(WQ[17]), "+v"(WQ[18]), "+v"(WQ[19]), \
                      "+v"(WQ[20]), "+v"(WQ[21]), "+v"(WQ[22]), "+v"(WQ[23]), \
                      "+v"(WQ[24]), "+v"(WQ[25]), "+v"(WQ[26]), "+v"(WQ[27]), \
                      "+v"(WQ[28]), "+v"(WQ[29]), "+v"(WQ[30]), "+v"(WQ[31])); \
    asm volatile("" : "+v"(WQ[32]), "+v"(WQ[33]), "+v"(WQ[34]), "+v"(WQ[35]), \
                      "+v"(WQ[36]), "+v"(WQ[37]), "+v"(WQ[38]), "+v"(WQ[39]), \
                      "+v"(WQ[40]), "+v"(WQ[41]), "+v"(WQ[42]), "+v"(WQ[43]), \
                      "+v"(WQ[44]), "+v"(WQ[45]), "+v"(WQ[46]), "+v"(WQ[47])); \
    asm volatile("" : "+v"(WQ[48]), "+v"(WQ[49]), "+v"(WQ[50]), "+v"(WQ[51]), \
                      "+v"(WQ[52]), "+v"(WQ[53]), "+v"(WQ[54]), "+v"(WQ[55]), \
                      "+v"(WQ[56]), "+v"(WQ[57]), "+v"(WQ[58]), "+v"(WQ[59]), \
                      "+v"(WQ[60]), "+v"(WQ[61]), "+v"(WQ[62]), "+v"(WQ[63])); \
} while (0)
#define PIND() \
    asm volatile("" : "+v"(DQ[0]),  "+v"(DQ[1]),  "+v"(DQ[2]),  "+v"(DQ[3]),  \
                      "+v"(DQ[4]),  "+v"(DQ[5]),  "+v"(DQ[6]),  "+v"(DQ[7]),  \
                      "+v"(DQ[8]),  "+v"(DQ[9]),  "+v"(DQ[10]), "+v"(DQ[11]), \
                      "+v"(DQ[12]), "+v"(DQ[13]), "+v"(DQ[14]), "+v"(DQ[15]))

// WQ[i*4+mh] = { Wh[32kk+2i][jb+2mh],   Wh[32kk+2i+1][jb+2mh],
//                Wh[32kk+2i][jb+2mh+1], Wh[32kk+2i+1][jb+2mh+1] } * SCL
#define LOAD_WH(WP) do { \
    _Pragma("unroll") \
    for (int i = 0; i < 16; ++i) { \
        _Pragma("unroll") \
        for (int mh = 0; mh < 4; ++mh) { \
            const float* bp = (WP) + (32 * kk + 2 * i) * H_ + jb + 2 * mh; \
            f32x2 ra = *(const f32x2*)(bp); \
            f32x2 rb = *(const f32x2*)(bp + H_); \
            WQ[i * 4 + mh] = (f32x4){ra.x * SCL, rb.x * SCL, ra.y * SCL, rb.y * SCL}; \
        } \
    } \
} while (0)

// 8 packed FMAs for k-pair i: accs A0..A7 cover cols jb+0..jb+7
#define ACC8(HP, i) do { f32x2 _hp = (HP); \
    EFMA(_hp, LO2(WQ[(i)*4+0]), A0); EFMA(_hp, HI2(WQ[(i)*4+0]), A1); \
    EFMA(_hp, LO2(WQ[(i)*4+1]), A2); EFMA(_hp, HI2(WQ[(i)*4+1]), A3); \
    EFMA(_hp, LO2(WQ[(i)*4+2]), A4); EFMA(_hp, HI2(WQ[(i)*4+2]), A5); \
    EFMA(_hp, LO2(WQ[(i)*4+3]), A6); EFMA(_hp, HI2(WQ[(i)*4+3]), A7); } while (0)

#define DACC(HP, i) do { f32x2 _hp = (HP); \
    EFMA(_hp, LO2(DQ[i]), D0); EFMA(_hp, HI2(DQ[i]), D1); } while (0)

// One RNN step (single wave — NO barrier; per-wave in-order LDS + lgkmcnt fence).
#define RNN_STEP(DENSEF, LOADPAIRF, IDP, TGB, DOSTORE, OUTP) do {                   \
    PINW();                                                                         \
    if (DENSEF) PIND();                                                             \
    int2 idpr_n = idpr;                                                             \
    if (LOADPAIRF) idpr_n = *(const int2*)((IDP) + 2);   /* ids[t+2..t+3] */        \
    float Ta_n = (TGB)[id_next * H_ + col0];             /* global prefetch t+1 */  \
    float Tb_n = (TGB)[id_next * H_ + col1];                                        \
    const f32x4* hq = (const f32x4*)(lds_h + rdbase);                               \
    f32x4 H0 = hq[0], H1 = hq[1], H2 = hq[2], H3 = hq[3];   /* 8x ds_read_b128 */   \
    f32x4 H4 = hq[4], H5 = hq[5], H6 = hq[6], H7 = hq[7];                           \
    f32x2 A0 = {0,0}, A1 = {0,0}, A2 = {0,0}, A3 = {0,0};                           \
    f32x2 A4 = {0,0}, A5 = {0,0}, A6 = {0,0}, A7 = {0,0};                           \
    ACC8(LO2(H0), 0);  ACC8(HI2(H0), 1);  ACC8(LO2(H1), 2);  ACC8(HI2(H1), 3);      \
    ACC8(LO2(H2), 4);  ACC8(HI2(H2), 5);  ACC8(LO2(H3), 6);  ACC8(HI2(H3), 7);      \
    ACC8(LO2(H4), 8);  ACC8(HI2(H4), 9);  ACC8(LO2(H5), 10); ACC8(HI2(H5), 11);     \
    ACC8(LO2(H6), 12); ACC8(HI2(H6), 13); ACC8(LO2(H7), 14); ACC8(HI2(H7), 15);     \
    float s0 = A0.x + A0.y, s1 = A1.x + A1.y, s2 = A2.x + A2.y, s3 = A3.x + A3.y;   \
    float s4 = A4.x + A4.y, s5 = A5.x + A5.y, s6 = A6.x + A6.y, s7 = A7.x + A7.y;   \
    float t0 = dpp_add<QP_1032>(s0), t1 = dpp_add<QP_1032>(s1);                     \
    float t2 = dpp_add<QP_1032>(s2), t3 = dpp_add<QP_1032>(s3);                     \
    float t4 = dpp_add<QP_1032>(s4), t5 = dpp_add<QP_1032>(s5);                     \
    float t6 = dpp_add<QP_1032>(s6), t7 = dpp_add<QP_1032>(s7);                     \
    float q0 = c0 ? t1 : t0, q1 = c0 ? t3 : t2;                                     \
    float q2 = c0 ? t5 : t4, q3 = c0 ? t7 : t6;                                     \
    float u0 = dpp_add<QP_2301>(q0), u1 = dpp_add<QP_2301>(q1);                     \
    float u2 = dpp_add<QP_2301>(q2), u3 = dpp_add<QP_2301>(q3);                     \
    float r0 = c1 ? u1 : u0;                             /* col jb+kk   */          \
    float r1 = c1 ? u3 : u2;                             /* col jb+kk+4 */          \
    float h0n = tanh_ps(r0 + Tva);                                                  \
    float h1n = tanh_ps(r1 + Tvb);                                                  \
    if (DENSEF) {                                        /* dense on h(t-1) */      \
        f32x2 D0 = {0,0}, D1 = {0,0};                                               \
        DACC(LO2(H0), 0);  DACC(HI2(H0), 1);  DACC(LO2(H1), 2);  DACC(HI2(H1), 3);  \
        DACC(LO2(H2), 4);  DACC(HI2(H2), 5);  DACC(LO2(H3), 6);  DACC(HI2(H3), 7);  \
        DACC(LO2(H4), 8);  DACC(HI2(H4), 9);  DACC(LO2(H5), 10); DACC(HI2(H5), 11); \
        DACC(LO2(H6), 12); DACC(HI2(H6), 13); DACC(LO2(H7), 14); DACC(HI2(H7), 15); \
        float d0 = D0.x + D0.y, d1 = D1.x + D1.y;                                   \
        d0 = dpp_add<QP_2301>(dpp_add<QP_1032>(d0));     /* full kk sum */          \
        d1 = dpp_add<QP_2301>(dpp_add<QP_1032>(d1));                                \
        if (DOSTORE) {                                   /* vmcnt never drained */  \
            if (st0) (OUTP)[0] = d0 + db0;                                          \
            if (st1) (OUTP)[1] = d1 + db1;                                          \
        }                                                                           \
    }                                                                               \
    lds_h[wr0] = h0n;                                    /* 2x ds_write_b32 */      \
    lds_h[wr1] = h1n;                                                               \
    asm volatile("s_waitcnt lgkmcnt(0)" ::: "memory");   /* write->read order */    \
    if (LOADPAIRF) { idpr = idpr_n; id_next = idpr_n.x; }                           \
    else           { id_next = idpr.y; }                                            \
    Tva = Ta_n; Tvb = Tb_n;                                                         \
} while (0)

__global__ __attribute__((amdgpu_flat_work_group_size(64, 64), amdgpu_waves_per_eu(1, 1)))
void seq2seq_rnn_kernel(const int* __restrict__ enc_ids, const int* __restrict__ dec_ids,
                        const float* __restrict__ enc_Wh, const float* __restrict__ dec_Wh,
                        const float* __restrict__ dense_W, const float* __restrict__ dense_b,
                        const float* __restrict__ Tg,      // [2][27][128] in d_ws (SCL-scaled)
                        float* __restrict__ out) {
    // h layout: k-chunk c (32 floats) at float offset 36*c — 16B-aligned quads,
    // chunk bases hit distinct bank quads (36c mod 32 = 4c).
    __shared__ __align__(16) float lds_h[144];
    __shared__ __align__(16) int   lds_ids[2 * S_ + 2];

    const int lane = threadIdx.x;                 // block == 1 wave of 64
    const int b    = blockIdx.x;
    const int kk   = lane & 3;                    // k-slice [32kk, 32kk+32)
    const int jg   = lane >> 2;                   // col group [8jg, 8jg+8)
    const int jb   = jg << 3;
    const int col0 = jb + kk;                     // this lane's output cols
    const int col1 = jb + kk + 4;
    const int wr0  = (col0 >> 5) * 36 + (col0 & 31);
    const int wr1  = (col1 >> 5) * 36 + (col1 & 31);
    const int rdbase = kk * 36;
    const bool c0 = (lane & 1) != 0;
    const bool c1 = (lane & 2) != 0;
    const int v0 = 2 * jg, v1 = v0 + 1;           // dense logit slots (27 of 32 used)
    const bool st0 = (kk == 0) && (v0 < V_);
    const bool st1 = (kk == 0) && (v1 < V_);

    // ---- stage ids (enc at [0,512), dec at [512,1024), sentinel pair); zero h ----
    {
        const int4* esrc = (const int4*)(enc_ids + b * S_);
        const int4* dsrc = (const int4*)(dec_ids + b * S_);
        int4* dst = (int4*)lds_ids;
        dst[lane]       = esrc[lane];
        dst[lane + 64]  = esrc[lane + 64];
        dst[lane + 128] = dsrc[lane];
        dst[lane + 192] = dsrc[lane + 64];
    }
    if (lane < 2) lds_ids[2 * S_ + lane] = 0;
    #pragma unroll
    for (int i = 0; i < 3; ++i) { int idx = lane + 64 * i; if (idx < 144) lds_h[idx] = 0.0f; }

    // ---- recurrent weights (encoder), pre-scaled by SCL: 64 f32x4 = 256 VGPRs ----
    f32x4 WQ[64];
    LOAD_WH(enc_Wh);

    f32x4 DQ[16];                                 // dense weights (loaded pre-decoder)
    float db0 = 0.0f, db1 = 0.0f;

    float* outd = out + b * (S_ * V_) + v0;
    asm volatile("s_waitcnt lgkmcnt(0)" ::: "memory");   // ids + h0 committed (1 wave)

    // ================= encoder: 512 steps =================
    {
        int2  idpr = make_int2(0, 0);
        int   id_next = lds_ids[1];
        float Tva = Tg[lds_ids[0] * H_ + col0];
        float Tvb = Tg[lds_ids[0] * H_ + col1];
        for (int t = 0; t < S_; t += 2) {
            RNN_STEP(false, true,  lds_ids + t, Tg, false, outd);
            RNN_STEP(false, false, lds_ids + t, Tg, false, outd);
        }
    }

    // ---- decoder weights + dense weights ----
    LOAD_WH(dec_Wh);
    {
        int vc0 = (v0 < V_) ? v0 : 0;
        int vc1 = (v1 < V_) ? v1 : 0;
        #pragma unroll
        for (int i = 0; i < 16; ++i) {
            const float* dp = dense_W + (32 * kk + 2 * i) * V_;
            DQ[i] = (f32x4){dp[vc0], dp[V_ + vc0], dp[vc1], dp[V_ + vc1]};
        }
        if (st0) db0 = dense_b[v0];
        if (st1) db1 = dense_b[v1];
    }

    // ================= decoder: 512 steps; dense piggybacked =================
    // Step t reads h(t-1) -> dense -> out[(t-1)*V].
    {
        const int*   ids_d = lds_ids + S_;
        const float* Td    = Tg + V_ * H_;
        int2  idpr = make_int2(0, 0);
        int   id_next = ids_d[1];
        float Tva = Td[ids_d[0] * H_ + col0];
        float Tvb = Td[ids_d[0] * H_ + col1];
        for (int t = 0; t < S_; t += 2) {
            RNN_STEP(true, true,  ids_d + t, Td, (t > 0), outd + (t - 1) * V_);
            RNN_STEP(true, false, ids_d + t, Td, true,    outd + t * V_);
        }
    }

    // epilogue: dense on final state h(511) -> logits[511]
    {
        asm volatile("s_waitcnt lgkmcnt(0)" ::: "memory");
        const f32x4* hq = (const f32x4*)(lds_h + rdbase);
        f32x4 H0 = hq[0], H1 = hq[1], H2 = hq[2], H3 = hq[3];
        f32x4 H4 = hq[4], H5 = hq[5], H6 = hq[6], H7 = hq[7];
        f32x2 D0 = {0,0}, D1 = {0,0};
        DACC(LO2(H0), 0);  DACC(HI2(H0), 1);  DACC(LO2(H1), 2);  DACC(HI2(H1), 3);
        DACC(LO2(H2), 4);  DACC(HI2(H2), 5);  DACC(LO2(H3), 6);  DACC(HI2(H3), 7);
        DACC(LO2(H4), 8);  DACC(HI2(H4), 9);  DACC(LO2(H5), 10); DACC(HI2(H5), 11);
        DACC(LO2(H6), 12); DACC(HI2(H6), 13); DACC(LO2(H7), 14); DACC(HI2(H7), 15);
        float d0 = D0.x + D0.y, d1 = D1.x + D1.y;
        d0 = dpp_add<QP_2301>(dpp_add<QP_1032>(d0));
        d1 = dpp_add<QP_2301>(dpp_add<QP_1032>(d1));
        if (st0) outd[(S_ - 1) * V_ + 0] = d0 + db0;
        if (st1) outd[(S_ - 1) * V_ + 1] = d1 + db1;
    }
}

extern "C" void kernel_launch(void* const* d_in, const int* in_sizes, int n_in,
                              void* d_out, int out_size, void* d_ws, size_t ws_size,
                              hipStream_t stream) {
    const int*   enc_ids = (const int*)d_in[0];
    const int*   dec_ids = (const int*)d_in[1];
    const float* embed   = (const float*)d_in[2];
    const float* enc_Wx  = (const float*)d_in[3];
    const float* enc_Wh  = (const float*)d_in[4];
    const float* enc_b   = (const float*)d_in[5];
    const float* dec_Wx  = (const float*)d_in[6];
    const float* dec_Wh  = (const float*)d_in[7];
    const float* dec_b   = (const float*)d_in[8];
    const float* dense_W = (const float*)d_in[9];
    const float* dense_b = (const float*)d_in[10];
    float* out = (float*)d_out;
    float* Tg  = (float*)d_ws;   // 2*27*128 floats = 27648 B

    hipLaunchKernelGGL(prep_T, dim3(2 * V_), dim3(H_), 0, stream,
                       embed, enc_Wx, enc_b, dec_Wx, dec_b, Tg);
    hipLaunchKernelGGL(seq2seq_rnn_kernel, dim3(256), dim3(64), 0, stream,
                       enc_ids, dec_ids, enc_Wh, dec_Wh, dense_W, dense_b, Tg, out);
}

// Round 7
// 354.459 us; speedup vs baseline: 5.3571x; 5.3571x over previous
//
#include <hip/hip_runtime.h>

// Problem constants: V=27, E=64, H=128, B=256, S=512 (enc and dec)
#define V_ 27
#define E_ 64
#define H_ 128
#define S_ 512
#define SCL 2.8853900817779268f   // 2*log2(e): tanh(z) = 1 - 2/(exp2(SCL*z)+1)

typedef float f32x2 __attribute__((ext_vector_type(2)));
typedef float f32x4 __attribute__((ext_vector_type(4)));

// Barrier WITHOUT vmcnt drain: LDS visibility only. Global loads/stores stay in flight.
#define BAR() asm volatile("s_waitcnt lgkmcnt(0)\n\ts_barrier" ::: "memory")

// ---- packed fp32 FMA (v_pk_fma_f32 on gfx950; fp32-exact) ----
#if __has_builtin(__builtin_elementwise_fma)
#define EFMA(H2, W2, A) (A) = __builtin_elementwise_fma((f32x2)(H2), (f32x2)(W2), (A))
#else
#define EFMA(H2, W2, A) do { f32x2 _h = (H2), _w = (W2); \
    (A).x = fmaf(_h.x, _w.x, (A).x); (A).y = fmaf(_h.y, _w.y, (A).y); } while (0)
#endif
#define LO2(Q) __builtin_shufflevector((Q), (Q), 0, 1)
#define HI2(Q) __builtin_shufflevector((Q), (Q), 2, 3)

// Per-iteration register pins: force weight residency (defeat load remat/sinking).
#define PINW() asm volatile("" : "+v"(WA[0]), "+v"(WA[1]), "+v"(WA[2]), "+v"(WA[3]), \
                                 "+v"(WA[4]), "+v"(WA[5]), "+v"(WA[6]), "+v"(WA[7]), \
                                 "+v"(WB[0]), "+v"(WB[1]), "+v"(WB[2]), "+v"(WB[3]), \
                                 "+v"(WB[4]), "+v"(WB[5]), "+v"(WB[6]), "+v"(WB[7]))
#define PIND() asm volatile("" : "+v"(DQ[0]), "+v"(DQ[1]), "+v"(DQ[2]), "+v"(DQ[3]))

// Hazard-safe DPP add (compiler inserts required wait states; raw asm DPP does not).
template<int CTRL>
__device__ __forceinline__ float dpp_add(float x) {
    int y = __builtin_amdgcn_update_dpp(0, __builtin_bit_cast(int, x), CTRL, 0xF, 0xF, true);
    return x + __builtin_bit_cast(float, y);
}
#define QP_1032 0xB1   // quad_perm [1,0,3,2]  (xor 1)
#define QP_2301 0x4E   // quad_perm [2,3,0,1]  (xor 2)
#define RR8 0x128      // row_ror:8 == xor 8 within a 16-lane row

// tanh from pre-scaled argument P = SCL*z:  tanh(z) = 1 - 2/(exp2(P)+1)
__device__ __forceinline__ float tanh_ps(float P) {
#if __has_builtin(__builtin_amdgcn_exp2f)
    float e = __builtin_amdgcn_exp2f(P);
#else
    float e = __expf(P * 0.69314718055994531f);
#endif
#if __has_builtin(__builtin_amdgcn_rcpf)
    float q = __builtin_amdgcn_rcpf(e + 1.0f);
    return fmaf(-2.0f, q, 1.0f);
#else
    return 1.0f - __fdividef(2.0f, e + 1.0f);
#endif
}

// ---------- prep kernel: T[tbl][v][j] = SCL*(b[j] + sum_e embed[v][e]*Wx[e][j]) ----------
__global__ void prep_T(const float* __restrict__ embed,
                       const float* __restrict__ eWx, const float* __restrict__ eb,
                       const float* __restrict__ dWx, const float* __restrict__ db_,
                       float* __restrict__ Tg) {
    int tbl = blockIdx.x / V_;
    int v   = blockIdx.x - tbl * V_;
    int j   = threadIdx.x;
    const float* Wx = tbl ? dWx : eWx;
    const float* bb = tbl ? db_ : eb;
    float s = bb[j];
    #pragma unroll
    for (int e = 0; e < E_; ++e) s = fmaf(embed[v * E_ + e], Wx[e * H_ + j], s);
    Tg[tbl * V_ * H_ + v * H_ + j] = s * SCL;
}

// k-pair weight quads (pre-scaled by SCL):
//   WA[i] = { W[16kk+2i][j0],   W[16kk+2i+1][j0],   W[16kk+2i][j0+1], W[16kk+2i+1][j0+1] }
//   WB[i] = same for cols j0+2, j0+3
#define LOADW(WH) do {                                                   \
    _Pragma("unroll")                                                    \
    for (int i = 0; i < 8; ++i) {                                        \
        const float* _a = (WH) + (16 * kk + 2 * i) * H_ + j0;            \
        f32x4 ra = *(const f32x4*)(_a);                                  \
        f32x4 rb = *(const f32x4*)(_a + H_);                             \
        WA[i] = (f32x4){ra.x * SCL, rb.x * SCL, ra.y * SCL, rb.y * SCL}; \
        WB[i] = (f32x4){ra.z * SCL, rb.z * SCL, ra.w * SCL, rb.w * SCL}; \
    }                                                                    \
} while (0)

// One k-pair: P0..P3 accumulate {even,odd}-k products for cols j0..j0+3
#define ACCP(HP, I) do { f32x2 _hp = (HP);              \
    EFMA(_hp, LO2(WA[I]), P0); EFMA(_hp, HI2(WA[I]), P1); \
    EFMA(_hp, LO2(WB[I]), P2); EFMA(_hp, HI2(WB[I]), P3); } while (0)

// One RNN step. DENSEF/LOADPAIRF are literal true/false (dead code eliminated).
#define RNN_STEP(HSRC, HDST, DENSEF, LOADPAIRF, IDP, TGB, DOSTORE, OUTP) do {       \
    PINW();                                                                         \
    if (DENSEF) PIND();                                                             \
    int2 idpr_n = idpr;                                                             \
    if (LOADPAIRF) idpr_n = *(const int2*)((IDP) + 2);   /* ids[t+2..t+3], b64 */   \
    float Tv_n = (TGB)[id_next * H_ + jd];               /* global prefetch t+1 */  \
    const f32x4* hbp = (const f32x4*)((HSRC) + 20 * kk);                            \
    f32x4 HA = hbp[0], HB = hbp[1], HC = hbp[2], HD = hbp[3]; /* 4x ds_read_b128 */ \
    f32x2 P0 = {0,0}, P1 = {0,0}, P2 = {0,0}, P3 = {0,0};                           \
    ACCP(LO2(HA), 0); ACCP(HI2(HA), 1); ACCP(LO2(HB), 2); ACCP(HI2(HB), 3);         \
    ACCP(LO2(HC), 4); ACCP(HI2(HC), 5); ACCP(LO2(HD), 6); ACCP(HI2(HD), 7);         \
    float s0 = P0.x + P0.y, s1 = P1.x + P1.y;                                       \
    float s2 = P2.x + P2.y, s3 = P3.x + P3.y;                                       \
    s0 = dpp_add<QP_2301>(dpp_add<QP_1032>(s0));                                    \
    s1 = dpp_add<QP_2301>(dpp_add<QP_1032>(s1));                                    \
    s2 = dpp_add<QP_2301>(dpp_add<QP_1032>(s2));                                    \
    s3 = dpp_add<QP_2301>(dpp_add<QP_1032>(s3));                                    \
    float s01 = c1 ? s1 : s0;                                                       \
    float s23 = c1 ? s3 : s2;                                                       \
    float r   = c2 ? s23 : s01;                                                     \
    r = dpp_add<RR8>(r);                                 /* xor8 = kk bit2 */       \
    float hnew = tanh_ps(r + Tv);                                                   \
    if (wrlane) (HDST)[wrword] = hnew;                   /* b32, 32 lanes/wave */   \
    if (DENSEF) {                                                                   \
        f32x2 E0 = {0,0}, E1 = {0,0};                                               \
        EFMA(LO2(HA), LO2(DQ[0]), E0); EFMA(HI2(HA), HI2(DQ[0]), E1);               \
        EFMA(LO2(HB), LO2(DQ[1]), E0); EFMA(HI2(HB), HI2(DQ[1]), E1);               \
        EFMA(LO2(HC), LO2(DQ[2]), E0); EFMA(HI2(HC), HI2(DQ[2]), E1);               \
        EFMA(LO2(HD), LO2(DQ[3]), E0); EFMA(HI2(HD), HI2(DQ[3]), E1);               \
        f32x2 E = E0 + E1;                                                          \
        float d = E.x + E.y;                                                        \
        d = dpp_add<RR8>(dpp_add<QP_2301>(dpp_add<QP_1032>(d)));                    \
        if (DOSTORE) (OUTP)[0] = d + db;                 /* vmcnt never drained */  \
    }                                                                               \
    BAR();                                                                          \
    if (LOADPAIRF) { idpr = idpr_n; id_next = idpr_n.x; }                           \
    else           { id_next = idpr.y; }                                            \
    Tv = Tv_n;                                                                      \
} while (0)

__global__ __attribute__((amdgpu_flat_work_group_size(256, 256), amdgpu_waves_per_eu(2, 2)))
void seq2seq_rnn_kernel(const int* __restrict__ enc_ids, const int* __restrict__ dec_ids,
                        const float* __restrict__ enc_Wh, const float* __restrict__ dec_Wh,
                        const float* __restrict__ dense_W, const float* __restrict__ dense_b,
                        const float* __restrict__ Tg,      // [2][27][128] in d_ws (SCL-scaled)
                        float* __restrict__ out) {
    __shared__ __align__(16) float lds_h0[160];   // 8 groups of 16, stride 20
    __shared__ __align__(16) float lds_h1[160];
    __shared__ __align__(16) int   lds_ids[2 * S_ + 2];

    const int tid  = threadIdx.x;
    const int b    = blockIdx.x;
    const int lane = tid & 63;
    const int w    = tid >> 6;                                    // 0..3
    // K-split index kk (8 chunks of 16 h-values): lane bits {0,1,3} -> DPP-reducible
    const int kk   = (lane & 3) | (((lane >> 3) & 1) << 2);
    // column-group index jl: lane bits {2,4,5}
    const int jl   = ((lane >> 2) & 1) | (((lane >> 4) & 3) << 1);
    const int j0     = (w << 5) + (jl << 2);                      // 4 cols per thread
    const int jd     = j0 + (lane & 3);                           // this lane's column
    const int wrword = 20 * (jd >> 4) + (jd & 15);                // stride-20 layout
    const bool wrlane = (lane & 8) == 0;                          // kk bit2 == 0
    const bool c1 = (lane & 1) != 0;
    const bool c2 = (lane & 2) != 0;
    const int vd   = (w << 3) | jl;               // dense logit slot (27 of 32 used)

    // ---- stage ids; zero h0 ----
    if (tid < 128) ((int4*)lds_ids)[tid] = ((const int4*)(enc_ids + b * S_))[tid];
    else ((int4*)(lds_ids + S_))[tid - 128] = ((const int4*)(dec_ids + b * S_))[tid - 128];
    if (tid < 2) lds_ids[2 * S_ + tid] = 0;
    if (tid < 160) lds_h0[tid] = 0.0f;

    // ---- recurrent weights: k-pair packed quads, 64 VGPRs, pre-scaled by SCL ----
    f32x4 WA[8], WB[8];
    LOADW(enc_Wh);

    // ---- dense weights: DQ[j] = dW[16kk+4j .. +3][vd] (4 rows per quad, unscaled) ----
    f32x4 DQ[4]; float db = 0.0f;
    {
        int vc = (vd < V_) ? vd : 0;
        const float* dp = dense_W + (16 * kk) * V_ + vc;
        DQ[0] = (f32x4){dp[ 0 * V_], dp[ 1 * V_], dp[ 2 * V_], dp[ 3 * V_]};
        DQ[1] = (f32x4){dp[ 4 * V_], dp[ 5 * V_], dp[ 6 * V_], dp[ 7 * V_]};
        DQ[2] = (f32x4){dp[ 8 * V_], dp[ 9 * V_], dp[10 * V_], dp[11 * V_]};
        DQ[3] = (f32x4){dp[12 * V_], dp[13 * V_], dp[14 * V_], dp[15 * V_]};
        if (vd < V_) db = dense_b[vd];
    }
    const bool dlane = ((lane & 11) == 0) && (vd < V_);    // kk==0 lanes
    float* outd = out + b * (S_ * V_) + vd;
    __syncthreads();   // ids + h0 ready

    // ================= encoder: 512 steps =================
    {
        int2  idpr = make_int2(0, 0);
        int   id_next = lds_ids[1];
        float Tv      = Tg[lds_ids[0] * H_ + jd];
        for (int t = 0; t < S_; t += 2) {
            RNN_STEP(lds_h0, lds_h1, false, true,  lds_ids + t, Tg, false, (float*)out);
            RNN_STEP(lds_h1, lds_h0, false, false, lds_ids + t, Tg, false, (float*)out);
        }
    }

    // ---- swap to decoder recurrent weights ----
    LOADW(dec_Wh);

    // ================= decoder: 512 steps; dense piggybacked =================
    // Step t reads buffer holding dec state after step t-1 -> dense -> out[(t-1)*V].
    {
        const int*   ids_d = lds_ids + S_;
        const float* Td    = Tg + V_ * H_;
        int2  idpr = make_int2(0, 0);
        int   id_next = ids_d[1];
        float Tv      = Td[ids_d[0] * H_ + jd];
        for (int t = 0; t < S_; t += 2) {
            RNN_STEP(lds_h0, lds_h1, true, true,  ids_d + t, Td,
                     dlane && (t > 0), outd + (t - 1) * V_);
            RNN_STEP(lds_h1, lds_h0, true, false, ids_d + t, Td,
                     dlane, outd + t * V_);
        }
    }

    // epilogue: dense on final state (decoder t=511 wrote lds_h0) -> logits[511]
    {
        const f32x4* hbp = (const f32x4*)(lds_h0 + 20 * kk);
        f32x4 HA = hbp[0], HB = hbp[1], HC = hbp[2], HD = hbp[3];
        f32x2 E0 = {0,0}, E1 = {0,0};
        EFMA(LO2(HA), LO2(DQ[0]), E0); EFMA(HI2(HA), HI2(DQ[0]), E1);
        EFMA(LO2(HB), LO2(DQ[1]), E0); EFMA(HI2(HB), HI2(DQ[1]), E1);
        EFMA(LO2(HC), LO2(DQ[2]), E0); EFMA(HI2(HC), HI2(DQ[2]), E1);
        EFMA(LO2(HD), LO2(DQ[3]), E0); EFMA(HI2(HD), HI2(DQ[3]), E1);
        f32x2 E = E0 + E1;
        float d = E.x + E.y;
        d = dpp_add<RR8>(dpp_add<QP_2301>(dpp_add<QP_1032>(d)));
        if (dlane) outd[(S_ - 1) * V_] = d + db;
    }
}

extern "C" void kernel_launch(void* const* d_in, const int* in_sizes, int n_in,
                              void* d_out, int out_size, void* d_ws, size_t ws_size,
                              hipStream_t stream) {
    const int*   enc_ids = (const int*)d_in[0];
    const int*   dec_ids = (const int*)d_in[1];
    const float* embed   = (const float*)d_in[2];
    const float* enc_Wx  = (const float*)d_in[3];
    const float* enc_Wh  = (const float*)d_in[4];
    const float* enc_b   = (const float*)d_in[5];
    const float* dec_Wx  = (const float*)d_in[6];
    const float* dec_Wh  = (const float*)d_in[7];
    const float* dec_b   = (const float*)d_in[8];
    const float* dense_W = (const float*)d_in[9];
    const float* dense_b = (const float*)d_in[10];
    float* out = (float*)d_out;
    float* Tg  = (float*)d_ws;   // 2*27*128 floats = 27648 B

    hipLaunchKernelGGL(prep_T, dim3(2 * V_), dim3(H_), 0, stream,
                       embed, enc_Wx, enc_b, dec_Wx, dec_b, Tg);
    hipLaunchKernelGGL(seq2seq_rnn_kernel, dim3(256), dim3(256), 0, stream,
                       enc_ids, dec_ids, enc_Wh, dec_Wh, dense_W, dense_b, Tg, out);
}